// Round 1
// baseline (658.919 us; speedup 1.0000x reference)
//
#include <hip/hip_runtime.h>

// VQ-VAE vector quantization for z:(32,256,32,32) f32, codebook:(1024,256) f32.
// Outputs (flat f32 in d_out): z_q (B,C,H,W) [8388608] | loss [1] | indices as float [32768].
//
// Distances: argmin_c ||c||^2 - 2 z.c  (||z||^2 constant per pixel, dropped).
// fp32 throughout: no fp32 MFMA on CDNA4; index threshold forbids argmin flips,
// so bf16 MFMA is unsafe without a rescore pass (future round).

#define EDIM   256
#define NCODE  1024
#define HWSZ   1024
#define NPIX   32768
#define LOSS_OFF 8388608
#define IDX_OFF  8388609

// ---------------------------------------------------------------------------
// Kernel 1: codebook squared norms + zero the loss accumulator.
__global__ __launch_bounds__(256) void vq_norms(const float* __restrict__ cb,
                                                float* __restrict__ cnorm,
                                                float* __restrict__ loss_slot)
{
    const int c = blockIdx.x * 256 + threadIdx.x;   // 4 blocks x 256 = 1024 codes
    if (c == 0) *loss_slot = 0.0f;                  // d_out is re-poisoned each launch
    const float4* row = reinterpret_cast<const float4*>(cb + (size_t)c * EDIM);
    float s = 0.0f;
#pragma unroll 8
    for (int k = 0; k < EDIM / 4; ++k) {
        const float4 v = row[k];
        s += v.x * v.x + v.y * v.y + v.z * v.z + v.w * v.w;
    }
    cnorm[c] = s;
}

// ---------------------------------------------------------------------------
// Kernel 2: fused distance-GEMM + argmin. One block = 64 pixels, all 1024 codes.
// LDS z-tile [k][pix] (exactly 64 KiB -> 2 blocks/CU). Wave w owns codes
// [w*256, (w+1)*256); codebook addresses are wave-uniform (scalar-load friendly).
__global__ __launch_bounds__(256) void vq_argmin(const float* __restrict__ z,
                                                 const float* __restrict__ cb,
                                                 const float* __restrict__ cnorm,
                                                 float* __restrict__ idx_out)
{
    __shared__ float zt[EDIM][64];   // 64 KiB; reused for the final reduction

    const int t   = threadIdx.x;
    const int n0  = blockIdx.x << 6;          // pixel base (512 blocks)
    const int bb  = n0 >> 10;                 // batch index (64 | 1024, no crossing)
    const int hw0 = n0 & 1023;
    const float* zbase = z + (size_t)bb * (EDIM * HWSZ) + hw0;

    // Stage z-tile: z[bb][c][hw0+p] -> zt[c][p]; coalesced float4 global loads.
    {
        const int pr = (t & 15) << 2;         // pixel offset 0..60 step 4
        const int c0 = t >> 4;                // 16 c-rows per iter
#pragma unroll
        for (int it = 0; it < 16; ++it) {
            const int c = (it << 4) + c0;
            const float4 v = *reinterpret_cast<const float4*>(zbase + c * HWSZ + pr);
            *reinterpret_cast<float4*>(&zt[c][pr]) = v;   // 16B-aligned
        }
    }
    __syncthreads();

    const int lane = t & 63;                               // = pixel within tile
    const int w    = __builtin_amdgcn_readfirstlane(t >> 6); // wave id 0..3 (SGPR)

    float best  = 3.402823e38f;
    int   besti = 0;

    for (int g = 0; g < 32; ++g) {
        const int cbase = (w << 8) | (g << 3);             // ascending code order
        const float* __restrict__ crow = cb + (size_t)cbase * EDIM;
        float acc[8] = {0.f, 0.f, 0.f, 0.f, 0.f, 0.f, 0.f, 0.f};
        for (int k = 0; k < EDIM; k += 4) {
            const float z0 = zt[k + 0][lane];              // 2-way bank alias: free
            const float z1 = zt[k + 1][lane];
            const float z2 = zt[k + 2][lane];
            const float z3 = zt[k + 3][lane];
#pragma unroll
            for (int j = 0; j < 8; ++j) {
                const float4 cv = *reinterpret_cast<const float4*>(crow + (j << 8) + k);
                acc[j] = fmaf(z0, cv.x, acc[j]);
                acc[j] = fmaf(z1, cv.y, acc[j]);
                acc[j] = fmaf(z2, cv.z, acc[j]);
                acc[j] = fmaf(z3, cv.w, acc[j]);
            }
        }
#pragma unroll
        for (int j = 0; j < 8; ++j) {
            const float d = fmaf(-2.0f, acc[j], cnorm[cbase + j]);
            if (d < best) { best = d; besti = cbase + j; } // strict <: first-min wins
        }
    }

    // Cross-wave argmin reduce (4 candidates per pixel), reusing zt.
    __syncthreads();                       // all waves done reading zt
    zt[w][lane]     = best;
    zt[4 + w][lane] = __int_as_float(besti);
    __syncthreads();
    if (t < 64) {
        float b  = zt[0][t];
        int   bi = __float_as_int(zt[4][t]);
#pragma unroll
        for (int ww = 1; ww < 4; ++ww) {
            const float v = zt[ww][t];
            if (v < b) { b = v; bi = __float_as_int(zt[4 + ww][t]); }
        }
        idx_out[n0 + t] = (float)bi;       // indices output, exact as f32
    }
}

// ---------------------------------------------------------------------------
// Kernel 3: gather z_q = codebook[idx], transpose-store to (B,C,H,W), fused
// MSE loss: codebook_loss = (1 + BETA) * mean((z_q - z)^2), BETA = 0.25.
__global__ __launch_bounds__(256) void vq_gather(const float* __restrict__ z,
                                                 const float* __restrict__ cb,
                                                 const float* __restrict__ idxf,
                                                 float* __restrict__ out)
{
    __shared__ float lq[64][129];   // 64 rows x 128 c-chunk, +1 pad -> conflict-free
    __shared__ int   sidx[64];

    const int t   = threadIdx.x;
    const int n0  = blockIdx.x << 6;
    const int bb  = n0 >> 10;
    const int hw0 = n0 & 1023;

    if (t < 64) sidx[t] = (int)idxf[n0 + t];

    const float* zb = z   + (size_t)bb * (EDIM * HWSZ) + hw0;
    float*       ob = out + (size_t)bb * (EDIM * HWSZ) + hw0;
    const int p  = t & 63;
    const int cq = t >> 6;
    float sum = 0.0f;

    for (int h = 0; h < 2; ++h) {           // two c-halves of 128
        __syncthreads();                    // sidx visible / lq reusable
#pragma unroll
        for (int i = 0; i < 8; ++i) {       // stage 64 code rows x 128 floats
            const int linear = (i << 8) + t;
            const int pr = linear >> 5;     // row 0..63
            const int f4 = (linear & 31) << 2;
            const float4 v = *reinterpret_cast<const float4*>(
                cb + (size_t)sidx[pr] * EDIM + (h << 7) + f4);
            float* dst = &lq[pr][f4];       // stride 129: scalar stores
            dst[0] = v.x; dst[1] = v.y; dst[2] = v.z; dst[3] = v.w;
        }
        __syncthreads();
#pragma unroll 4
        for (int r = 0; r < 32; ++r) {      // coalesced stores: 64 consecutive hw
            const int c  = (r << 2) + cq;
            const int cf = (h << 7) + c;
            const float q  = lq[p][c];      // banks (p+c)%32: 2-way, free
            const float zv = zb[cf * HWSZ + p];
            ob[cf * HWSZ + p] = q;
            const float dd = q - zv;
            sum = fmaf(dd, dd, sum);
        }
    }

#pragma unroll
    for (int m = 32; m; m >>= 1) sum += __shfl_xor(sum, m, 64);
    if (p == 0) atomicAdd(out + LOSS_OFF, sum * (1.25f / 8388608.0f));
}

// ---------------------------------------------------------------------------
extern "C" void kernel_launch(void* const* d_in, const int* in_sizes, int n_in,
                              void* d_out, int out_size, void* d_ws, size_t ws_size,
                              hipStream_t stream)
{
    const float* z  = (const float*)d_in[0];
    const float* cb = (const float*)d_in[1];
    float* out = (float*)d_out;
    // cnorm scratch: d_ws if big enough, else park in the z_q region (it is
    // fully overwritten by vq_gather after vq_argmin has consumed cnorm).
    float* cnorm = (ws_size >= (size_t)(NCODE * sizeof(float))) ? (float*)d_ws : out;

    vq_norms <<<NCODE / 256, 256, 0, stream>>>(cb, cnorm, out + LOSS_OFF);
    vq_argmin<<<NPIX / 64,  256, 0, stream>>>(z, cb, cnorm, out + IDX_OFF);
    vq_gather<<<NPIX / 64,  256, 0, stream>>>(z, cb, out + IDX_OFF, out);
}

// Round 2
// 581.180 us; speedup vs baseline: 1.1338x; 1.1338x over previous
//
#include <hip/hip_runtime.h>

// VQ-VAE vector quantization for z:(32,256,32,32) f32, codebook:(1024,256) f32.
// Outputs (flat f32 in d_out): z_q (B,C,H,W) [8388608] | loss [1] | indices as float [32768].
//
// Round 2: argmin kernel restructured. Round-1 profile: VALUBusy 24% -> the
// wave-uniform global codebook loads in the inner loop stalled on L2 latency
// at 2 waves/SIMD. Now: codebook chunk in REGISTERS (per-lane code, reused
// across 16 pixels), z-tile in LDS read via wave-uniform broadcast
// ds_read_b128. Target: VALU-FMA-bound (~109 us roofline for 17.2 GFLOP).

#define EDIM   256
#define NCODE  1024
#define HWSZ   1024
#define NPIX   32768
#define LOSS_OFF 8388608
#define IDX_OFF  8388609

#define PTILE  16     // pixels per block
#define ZPAD   260    // zt row stride in floats: %4==0 (b128 align), %32==4 (2-way write conflicts only)

// ---------------------------------------------------------------------------
// Kernel 1: codebook squared norms + zero the loss accumulator.
__global__ __launch_bounds__(256) void vq_norms(const float* __restrict__ cb,
                                                float* __restrict__ cnorm,
                                                float* __restrict__ loss_slot)
{
    const int c = blockIdx.x * 256 + threadIdx.x;   // 4 blocks x 256 = 1024 codes
    if (c == 0) *loss_slot = 0.0f;                  // d_out is re-poisoned each launch
    const float4* row = reinterpret_cast<const float4*>(cb + (size_t)c * EDIM);
    float s = 0.0f;
#pragma unroll 8
    for (int k = 0; k < EDIM / 4; ++k) {
        const float4 v = row[k];
        s += v.x * v.x + v.y * v.y + v.z * v.z + v.w * v.w;
    }
    cnorm[c] = s;
}

// ---------------------------------------------------------------------------
// Kernel 2: fused distance-GEMM + argmin.
// Block = 256 thr (4 waves) x 16 pixels. Lane l of wave w owns code
// cg*256 + w*64 + l for cg = 0..3. Codebook chunk (32 floats) lives in VGPRs,
// reused across all 16 pixels; z comes from LDS via broadcast ds_read_b128.
__global__ __launch_bounds__(256, 4) void vq_argmin(const float* __restrict__ z,
                                                    const float* __restrict__ cb,
                                                    const float* __restrict__ cnorm,
                                                    float* __restrict__ idx_out)
{
    __shared__ float zt[PTILE][ZPAD];    // ~16.3 KiB
    __shared__ float redv[4][PTILE];
    __shared__ int   redi[4][PTILE];

    const int t   = threadIdx.x;
    const int n0  = blockIdx.x * PTILE;       // 2048 blocks
    const int bb  = n0 >> 10;                 // batch (16 | 1024: no crossing)
    const int hw0 = n0 & 1023;
    const float* zbase = z + (size_t)bb * (EDIM * HWSZ) + hw0;

    // Stage z-tile: zt[p][c] = z[bb][c][hw0+p]. float4 along hw, transposed
    // scalar LDS writes (2-way bank alias with ZPAD=260: free).
#pragma unroll
    for (int i = 0; i < 4; ++i) {
        const int linear = (i << 8) + t;      // 0..1023
        const int c  = linear >> 2;
        const int p4 = (linear & 3) << 2;
        const float4 v = *reinterpret_cast<const float4*>(zbase + c * HWSZ + p4);
        zt[p4 + 0][c] = v.x;
        zt[p4 + 1][c] = v.y;
        zt[p4 + 2][c] = v.z;
        zt[p4 + 3][c] = v.w;
    }
    __syncthreads();

    const int lane = t & 63;
    const int w    = t >> 6;

    float best[PTILE];
    int   besti[PTILE];
#pragma unroll
    for (int p = 0; p < PTILE; ++p) { best[p] = 3.402823e38f; besti[p] = 0; }

    for (int cg = 0; cg < 4; ++cg) {
        const int code = (cg << 8) | (w << 6) | lane;
        const float4* __restrict__ crow =
            reinterpret_cast<const float4*>(cb + (size_t)code * EDIM);
        const float cn = cnorm[code];

        float acc[PTILE];
#pragma unroll
        for (int p = 0; p < PTILE; ++p) acc[p] = 0.0f;

        for (int kc = 0; kc < 8; ++kc) {      // K chunks of 32
            float4 cv[8];
#pragma unroll
            for (int j = 0; j < 8; ++j) cv[j] = crow[(kc << 3) + j];  // 32 VGPRs, L2-hot
#pragma unroll
            for (int p = 0; p < PTILE; ++p) {
                const float4* __restrict__ zp =
                    reinterpret_cast<const float4*>(&zt[p][kc << 5]); // wave-uniform -> broadcast
#pragma unroll
                for (int j = 0; j < 8; ++j) {
                    const float4 zv = zp[j];
                    acc[p] = fmaf(cv[j].x, zv.x, acc[p]);
                    acc[p] = fmaf(cv[j].y, zv.y, acc[p]);
                    acc[p] = fmaf(cv[j].z, zv.z, acc[p]);
                    acc[p] = fmaf(cv[j].w, zv.w, acc[p]);
                }
            }
        }
#pragma unroll
        for (int p = 0; p < PTILE; ++p) {
            const float d = fmaf(-2.0f, acc[p], cn);
            if (d < best[p]) { best[p] = d; besti[p] = code; }  // ascending cg: first-min
        }
    }

    // Argmin reduce: butterfly across 64 lanes with (val, idx) tie-break
    // (equal values -> smaller index, matching numpy first-occurrence).
#pragma unroll
    for (int p = 0; p < PTILE; ++p) {
        float v  = best[p];
        int   vi = besti[p];
#pragma unroll
        for (int m = 1; m < 64; m <<= 1) {
            const float ov  = __shfl_xor(v, m, 64);
            const int   ovi = __shfl_xor(vi, m, 64);
            if (ov < v || (ov == v && ovi < vi)) { v = ov; vi = ovi; }
        }
        if (lane == 0) { redv[w][p] = v; redi[w][p] = vi; }
    }
    __syncthreads();
    if (t < PTILE) {
        float b  = redv[0][t];
        int   bi = redi[0][t];
#pragma unroll
        for (int ww = 1; ww < 4; ++ww) {
            const float v  = redv[ww][t];
            const int   vi = redi[ww][t];
            if (v < b || (v == b && vi < bi)) { b = v; bi = vi; }
        }
        idx_out[n0 + t] = (float)bi;          // exact as f32 (0..1023)
    }
}

// ---------------------------------------------------------------------------
// Kernel 3: gather z_q = codebook[idx], transpose-store to (B,C,H,W), fused
// MSE loss: codebook_loss = (1 + BETA) * mean((z_q - z)^2), BETA = 0.25.
__global__ __launch_bounds__(256) void vq_gather(const float* __restrict__ z,
                                                 const float* __restrict__ cb,
                                                 const float* __restrict__ idxf,
                                                 float* __restrict__ out)
{
    __shared__ float lq[64][129];   // 64 rows x 128 c-chunk, +1 pad -> conflict-free
    __shared__ int   sidx[64];

    const int t   = threadIdx.x;
    const int n0  = blockIdx.x << 6;
    const int bb  = n0 >> 10;
    const int hw0 = n0 & 1023;

    if (t < 64) sidx[t] = (int)idxf[n0 + t];

    const float* zb = z   + (size_t)bb * (EDIM * HWSZ) + hw0;
    float*       ob = out + (size_t)bb * (EDIM * HWSZ) + hw0;
    const int p  = t & 63;
    const int cq = t >> 6;
    float sum = 0.0f;

    for (int h = 0; h < 2; ++h) {           // two c-halves of 128
        __syncthreads();                    // sidx visible / lq reusable
#pragma unroll
        for (int i = 0; i < 8; ++i) {       // stage 64 code rows x 128 floats
            const int linear = (i << 8) + t;
            const int pr = linear >> 5;     // row 0..63
            const int f4 = (linear & 31) << 2;
            const float4 v = *reinterpret_cast<const float4*>(
                cb + (size_t)sidx[pr] * EDIM + (h << 7) + f4);
            float* dst = &lq[pr][f4];       // stride 129: scalar stores
            dst[0] = v.x; dst[1] = v.y; dst[2] = v.z; dst[3] = v.w;
        }
        __syncthreads();
#pragma unroll 4
        for (int r = 0; r < 32; ++r) {      // coalesced stores: 64 consecutive hw
            const int c  = (r << 2) + cq;
            const int cf = (h << 7) + c;
            const float q  = lq[p][c];      // banks (p+c)%32: 2-way, free
            const float zv = zb[cf * HWSZ + p];
            ob[cf * HWSZ + p] = q;
            const float dd = q - zv;
            sum = fmaf(dd, dd, sum);
        }
    }

#pragma unroll
    for (int m = 32; m; m >>= 1) sum += __shfl_xor(sum, m, 64);
    if (p == 0) atomicAdd(out + LOSS_OFF, sum * (1.25f / 8388608.0f));
}

// ---------------------------------------------------------------------------
extern "C" void kernel_launch(void* const* d_in, const int* in_sizes, int n_in,
                              void* d_out, int out_size, void* d_ws, size_t ws_size,
                              hipStream_t stream)
{
    const float* z  = (const float*)d_in[0];
    const float* cb = (const float*)d_in[1];
    float* out = (float*)d_out;
    // cnorm scratch: d_ws if big enough, else park in the z_q region (it is
    // fully overwritten by vq_gather after vq_argmin has consumed cnorm).
    float* cnorm = (ws_size >= (size_t)(NCODE * sizeof(float))) ? (float*)d_ws : out;

    vq_norms <<<NCODE / 256,  256, 0, stream>>>(cb, cnorm, out + LOSS_OFF);
    vq_argmin<<<NPIX / PTILE, 256, 0, stream>>>(z, cb, cnorm, out + IDX_OFF);
    vq_gather<<<NPIX / 64,    256, 0, stream>>>(z, cb, out + IDX_OFF, out);
}

// Round 3
// 433.105 us; speedup vs baseline: 1.5214x; 1.3419x over previous
//
#include <hip/hip_runtime.h>

// VQ-VAE vector quantization for z:(32,256,32,32) f32, codebook:(1024,256) f32.
// Outputs (flat f32 in d_out): z_q (B,C,H,W) [8388608] | loss [1] | indices as float [32768].
//
// Round 3: fix AGPR-spill found in round 2 (VGPR_Count=64 with ~110 live regs
// -> v_accvgpr_read/write around every FMA -> 3.3x VALU inflation, VALUBusy 67%
// at 548us). Changes: __launch_bounds__(256,3) (168-reg cap), K-chunk 32->16,
// 2 codes/lane (halves LDS z-reads per FMA: one broadcast b128 feeds 8 FMAs).
// Target: VALU-FMA-bound, ~109us GEMM floor + overhead.

#define EDIM   256
#define NCODE  1024
#define HWSZ   1024
#define NPIX   32768
#define LOSS_OFF 8388608
#define IDX_OFF  8388609

#define PTILE  16     // pixels per block
#define ZPAD   260    // zt row stride in floats: %4==0 (b128 align), 2-way write alias only

// ---------------------------------------------------------------------------
// Kernel 1: codebook squared norms + zero the loss accumulator.
__global__ __launch_bounds__(256) void vq_norms(const float* __restrict__ cb,
                                                float* __restrict__ cnorm,
                                                float* __restrict__ loss_slot)
{
    const int c = blockIdx.x * 256 + threadIdx.x;   // 4 blocks x 256 = 1024 codes
    if (c == 0) *loss_slot = 0.0f;                  // d_out is re-poisoned each launch
    const float4* row = reinterpret_cast<const float4*>(cb + (size_t)c * EDIM);
    float s = 0.0f;
#pragma unroll 8
    for (int k = 0; k < EDIM / 4; ++k) {
        const float4 v = row[k];
        s += v.x * v.x + v.y * v.y + v.z * v.z + v.w * v.w;
    }
    cnorm[c] = s;
}

// ---------------------------------------------------------------------------
// Kernel 2: fused distance-GEMM + argmin.
// Block = 256 thr (4 waves) x 16 pixels. Lane l of wave w owns TWO codes per
// pass: c0 = cg*512 + w*64 + l and c1 = c0 + 256 (cg = 0,1). Codebook K-chunk
// (16 floats/code) in VGPRs, reused across 16 pixels; z from LDS via broadcast
// ds_read_b128 (each read feeds 8 FMAs).
__global__ __launch_bounds__(256, 3) void vq_argmin(const float* __restrict__ z,
                                                    const float* __restrict__ cb,
                                                    const float* __restrict__ cnorm,
                                                    float* __restrict__ idx_out)
{
    __shared__ float zt[PTILE][ZPAD];    // ~16.3 KiB
    __shared__ float redv[4][PTILE];
    __shared__ int   redi[4][PTILE];

    const int t   = threadIdx.x;
    const int n0  = blockIdx.x * PTILE;       // 2048 blocks
    const int bb  = n0 >> 10;                 // batch (16 | 1024: no crossing)
    const int hw0 = n0 & 1023;
    const float* zbase = z + (size_t)bb * (EDIM * HWSZ) + hw0;

    // Stage z-tile: zt[p][c] = z[bb][c][hw0+p]. float4 along hw, transposed
    // scalar LDS writes (2-way bank alias with ZPAD=260: free).
#pragma unroll
    for (int i = 0; i < 4; ++i) {
        const int linear = (i << 8) + t;      // 0..1023
        const int c  = linear >> 2;
        const int p4 = (linear & 3) << 2;
        const float4 v = *reinterpret_cast<const float4*>(zbase + c * HWSZ + p4);
        zt[p4 + 0][c] = v.x;
        zt[p4 + 1][c] = v.y;
        zt[p4 + 2][c] = v.z;
        zt[p4 + 3][c] = v.w;
    }
    __syncthreads();

    const int lane = t & 63;
    const int w    = t >> 6;
    const int cwl  = (w << 6) | lane;         // 0..255

    float best[PTILE];
    int   besti[PTILE];
#pragma unroll
    for (int p = 0; p < PTILE; ++p) { best[p] = 3.402823e38f; besti[p] = 0; }

    for (int cg = 0; cg < 2; ++cg) {
        const int c0 = (cg << 9) | cwl;       // ascending within lane across cg
        const int c1 = c0 + 256;
        const float4* __restrict__ crow0 =
            reinterpret_cast<const float4*>(cb + (size_t)c0 * EDIM);
        const float4* __restrict__ crow1 =
            reinterpret_cast<const float4*>(cb + (size_t)c1 * EDIM);

        float acc0[PTILE], acc1[PTILE];
#pragma unroll
        for (int p = 0; p < PTILE; ++p) { acc0[p] = 0.0f; acc1[p] = 0.0f; }

        for (int kc = 0; kc < 16; ++kc) {     // K chunks of 16
            float4 cv0[4], cv1[4];
#pragma unroll
            for (int j = 0; j < 4; ++j) cv0[j] = crow0[(kc << 2) + j];
#pragma unroll
            for (int j = 0; j < 4; ++j) cv1[j] = crow1[(kc << 2) + j];
#pragma unroll
            for (int p = 0; p < PTILE; ++p) {
                const float4* __restrict__ zp =
                    reinterpret_cast<const float4*>(&zt[p][kc << 4]); // uniform -> broadcast
#pragma unroll
                for (int j = 0; j < 4; ++j) {
                    const float4 zv = zp[j];
                    acc0[p] = fmaf(cv0[j].x, zv.x, acc0[p]);
                    acc0[p] = fmaf(cv0[j].y, zv.y, acc0[p]);
                    acc0[p] = fmaf(cv0[j].z, zv.z, acc0[p]);
                    acc0[p] = fmaf(cv0[j].w, zv.w, acc0[p]);
                    acc1[p] = fmaf(cv1[j].x, zv.x, acc1[p]);
                    acc1[p] = fmaf(cv1[j].y, zv.y, acc1[p]);
                    acc1[p] = fmaf(cv1[j].z, zv.z, acc1[p]);
                    acc1[p] = fmaf(cv1[j].w, zv.w, acc1[p]);
                }
            }
        }

        const float cn0 = cnorm[c0];
        const float cn1 = cnorm[c1];
#pragma unroll
        for (int p = 0; p < PTILE; ++p) {
            const float d0 = fmaf(-2.0f, acc0[p], cn0);
            const float d1 = fmaf(-2.0f, acc1[p], cn1);
            // strict <, candidates processed in ascending code index -> first-min
            if (d0 < best[p]) { best[p] = d0; besti[p] = c0; }
            if (d1 < best[p]) { best[p] = d1; besti[p] = c1; }
        }
    }

    // Argmin reduce: butterfly across 64 lanes with (val, idx) tie-break
    // (equal values -> smaller index, matching numpy first-occurrence).
#pragma unroll
    for (int p = 0; p < PTILE; ++p) {
        float v  = best[p];
        int   vi = besti[p];
#pragma unroll
        for (int m = 1; m < 64; m <<= 1) {
            const float ov  = __shfl_xor(v, m, 64);
            const int   ovi = __shfl_xor(vi, m, 64);
            if (ov < v || (ov == v && ovi < vi)) { v = ov; vi = ovi; }
        }
        if (lane == 0) { redv[w][p] = v; redi[w][p] = vi; }
    }
    __syncthreads();
    if (t < PTILE) {
        float b  = redv[0][t];
        int   bi = redi[0][t];
#pragma unroll
        for (int ww = 1; ww < 4; ++ww) {
            const float v  = redv[ww][t];
            const int   vi = redi[ww][t];
            if (v < b || (v == b && vi < bi)) { b = v; bi = vi; }
        }
        idx_out[n0 + t] = (float)bi;          // exact as f32 (0..1023)
    }
}

// ---------------------------------------------------------------------------
// Kernel 3: gather z_q = codebook[idx], transpose-store to (B,C,H,W), fused
// MSE loss: codebook_loss = (1 + BETA) * mean((z_q - z)^2), BETA = 0.25.
__global__ __launch_bounds__(256) void vq_gather(const float* __restrict__ z,
                                                 const float* __restrict__ cb,
                                                 const float* __restrict__ idxf,
                                                 float* __restrict__ out)
{
    __shared__ float lq[64][129];   // 64 rows x 128 c-chunk, +1 pad -> conflict-free
    __shared__ int   sidx[64];

    const int t   = threadIdx.x;
    const int n0  = blockIdx.x << 6;
    const int bb  = n0 >> 10;
    const int hw0 = n0 & 1023;

    if (t < 64) sidx[t] = (int)idxf[n0 + t];

    const float* zb = z   + (size_t)bb * (EDIM * HWSZ) + hw0;
    float*       ob = out + (size_t)bb * (EDIM * HWSZ) + hw0;
    const int p  = t & 63;
    const int cq = t >> 6;
    float sum = 0.0f;

    for (int h = 0; h < 2; ++h) {           // two c-halves of 128
        __syncthreads();                    // sidx visible / lq reusable
#pragma unroll
        for (int i = 0; i < 8; ++i) {       // stage 64 code rows x 128 floats
            const int linear = (i << 8) + t;
            const int pr = linear >> 5;     // row 0..63
            const int f4 = (linear & 31) << 2;
            const float4 v = *reinterpret_cast<const float4*>(
                cb + (size_t)sidx[pr] * EDIM + (h << 7) + f4);
            float* dst = &lq[pr][f4];       // stride 129: scalar stores
            dst[0] = v.x; dst[1] = v.y; dst[2] = v.z; dst[3] = v.w;
        }
        __syncthreads();
#pragma unroll 4
        for (int r = 0; r < 32; ++r) {      // coalesced stores: 64 consecutive hw
            const int c  = (r << 2) + cq;
            const int cf = (h << 7) + c;
            const float q  = lq[p][c];      // banks (p+c)%32: 2-way, free
            const float zv = zb[cf * HWSZ + p];
            ob[cf * HWSZ + p] = q;
            const float dd = q - zv;
            sum = fmaf(dd, dd, sum);
        }
    }

#pragma unroll
    for (int m = 32; m; m >>= 1) sum += __shfl_xor(sum, m, 64);
    if (p == 0) atomicAdd(out + LOSS_OFF, sum * (1.25f / 8388608.0f));
}

// ---------------------------------------------------------------------------
extern "C" void kernel_launch(void* const* d_in, const int* in_sizes, int n_in,
                              void* d_out, int out_size, void* d_ws, size_t ws_size,
                              hipStream_t stream)
{
    const float* z  = (const float*)d_in[0];
    const float* cb = (const float*)d_in[1];
    float* out = (float*)d_out;
    // cnorm scratch: d_ws if big enough, else park in the z_q region (it is
    // fully overwritten by vq_gather after vq_argmin has consumed cnorm).
    float* cnorm = (ws_size >= (size_t)(NCODE * sizeof(float))) ? (float*)d_ws : out;

    vq_norms <<<NCODE / 256,  256, 0, stream>>>(cb, cnorm, out + LOSS_OFF);
    vq_argmin<<<NPIX / PTILE, 256, 0, stream>>>(z, cb, cnorm, out + IDX_OFF);
    vq_gather<<<NPIX / 64,    256, 0, stream>>>(z, cb, out + IDX_OFF, out);
}

// Round 5
// 224.695 us; speedup vs baseline: 2.9325x; 1.9275x over previous
//
#include <hip/hip_runtime.h>

// VQ-VAE vector quantization for z:(32,256,32,32) f32, codebook:(1024,256) f32.
// Outputs (flat f32 in d_out): z_q (B,C,H,W) [8388608] | loss [1] | indices as float [32768].
//
// Round 5: resubmit of round-4 MFMA engine (container infra failure, no bench).
// Scheme:
//   - hi/lo bf16 split of z and codebook: <z,c> = hi.hi + lo.hi + hi.lo (3 MFMA
//     passes, 16x16x32_bf16). Approx error <= ~3e-3 worst, ~3e-5 typical.
//   - per-pixel top-2 tracking; gap > THR=0.02 proves argmin exact; else exact
//     fp32 fallback on the two candidates (expected ~40 pixels / 32768).
//   - prep kernel transposes z into pixel-major bf16 hi/lo planes stored in the
//     z_q output region (dead until vq_gather overwrites it; exactly 32 MB).
//   - codebook converted f32->bf16 during LDS staging; ||c||^2 accumulated in
//     the same pass (no cnorm kernel, d_ws unused).

#define EDIM   256
#define NCODE  1024
#define HWSZ   1024
#define NPIX   32768
#define LOSS_OFF 8388608
#define IDX_OFF  8388609
#define THR    0.02f

typedef __attribute__((ext_vector_type(8))) short s16x8;   // 8 bf16 = 4 VGPR (MFMA A/B frag)
typedef __attribute__((ext_vector_type(4))) float f32x4;   // MFMA C/D frag

__device__ inline unsigned short f2bf(float f) {           // RNE f32 -> bf16
    unsigned u = __float_as_uint(f);
    return (unsigned short)((u + 0x7FFFu + ((u >> 16) & 1u)) >> 16);
}
__device__ inline float bf2f(unsigned short h) { return __uint_as_float(((unsigned)h) << 16); }

// ---------------------------------------------------------------------------
// Kernel 1: transpose z (B,C,HW) f32 -> pixel-major bf16 planes zhi[n][k],
// zlo[n][k] (n = b*1024+hw, k = channel). Also zeroes the loss slot.
__global__ __launch_bounds__(256) void vq_prep(const float* __restrict__ z,
                                               unsigned short* __restrict__ zhi,
                                               unsigned short* __restrict__ zlo,
                                               float* __restrict__ loss_slot)
{
    __shared__ unsigned lzp[64][68];          // packed hi|lo<<16, 64 px x 64 k slab

    const int t  = threadIdx.x;
    const int n0 = blockIdx.x << 6;           // 512 blocks x 64 px
    const int bb = n0 >> 10, hw0 = n0 & 1023;
    if (blockIdx.x == 0 && t == 0) *loss_slot = 0.0f;
    const float* zb = z + (size_t)bb * (EDIM * HWSZ) + hw0;

    for (int pk = 0; pk < 4; ++pk) {          // 4 k-slabs of 64
#pragma unroll
        for (int i = 0; i < 4; ++i) {         // 64k x 64px = 1024 float4
            const int linear = (i << 8) + t;
            const int kk  = linear >> 4;
            const int px4 = (linear & 15) << 2;
            const float4 v = *reinterpret_cast<const float4*>(zb + (pk * 64 + kk) * HWSZ + px4);
            const float vv[4] = {v.x, v.y, v.z, v.w};
#pragma unroll
            for (int j = 0; j < 4; ++j) {
                const unsigned short h = f2bf(vv[j]);
                const unsigned short l = f2bf(vv[j] - bf2f(h));
                lzp[px4 + j][kk] = (unsigned)h | ((unsigned)l << 16);
            }
        }
        __syncthreads();
        {
            const int px = t >> 2, kq = (t & 3) << 4;     // 16 k per thread
            const uint4 q0 = *(const uint4*)&lzp[px][kq];
            const uint4 q1 = *(const uint4*)&lzp[px][kq + 4];
            const uint4 q2 = *(const uint4*)&lzp[px][kq + 8];
            const uint4 q3 = *(const uint4*)&lzp[px][kq + 12];
            #define PH(a,b) (((a) & 0xffffu) | ((b) << 16))
            #define PL(a,b) (((a) >> 16) | ((b) & 0xffff0000u))
            const uint4 hA = {PH(q0.x,q0.y), PH(q0.z,q0.w), PH(q1.x,q1.y), PH(q1.z,q1.w)};
            const uint4 hB = {PH(q2.x,q2.y), PH(q2.z,q2.w), PH(q3.x,q3.y), PH(q3.z,q3.w)};
            const uint4 lA = {PL(q0.x,q0.y), PL(q0.z,q0.w), PL(q1.x,q1.y), PL(q1.z,q1.w)};
            const uint4 lB = {PL(q2.x,q2.y), PL(q2.z,q2.w), PL(q3.x,q3.y), PL(q3.z,q3.w)};
            #undef PH
            #undef PL
            const size_t off = (size_t)(n0 + px) * EDIM + pk * 64 + kq;
            *(uint4*)(zhi + off)     = hA;  *(uint4*)(zhi + off + 8) = hB;
            *(uint4*)(zlo + off)     = lA;  *(uint4*)(zlo + off + 8) = lB;
        }
        __syncthreads();
    }
}

// ---------------------------------------------------------------------------
// Kernel 2: MFMA distance GEMM + exact argmin.
// Block: 256 thr (4 waves) x 64 pixels x all 1024 codes (4 groups of 256).
// Wave w owns codes w*64..w*64+63 of the group: 4 M-frags x 4 N-frags.
__global__ __launch_bounds__(256, 2) void vq_argmin(const float* __restrict__ z,
                                                    const float* __restrict__ cb,
                                                    const unsigned short* __restrict__ zhi,
                                                    const unsigned short* __restrict__ zlo,
                                                    float* __restrict__ idx_out)
{
    __shared__ unsigned short cbt[2][256][32]; // [hi/lo][code][k] 32 KiB
    __shared__ unsigned short zt [2][64][32];  // [hi/lo][px][k]    8 KiB
    __shared__ float cn[256];
    __shared__ float rb1[4][64], rb2[4][64];
    __shared__ int   ri1[4][64], ri2[4][64];
    __shared__ int   fl_cnt, fl_px[64], fl_i1[64], fl_i2[64];
    __shared__ float fred[2][4];

    const int t    = threadIdx.x;
    const int lane = t & 63;
    const int w    = t >> 6;
    const int n0   = blockIdx.x << 6;          // 512 blocks
    const int bb   = n0 >> 10, hw0 = n0 & 1023;
    const int l15  = lane & 15, kq = lane >> 4;

    float b1[4], b2[4]; int i1[4], i2[4];
#pragma unroll
    for (int nf = 0; nf < 4; ++nf) { b1[nf] = 3.402823e38f; b2[nf] = 3.402823e38f; i1[nf] = 0; i2[nf] = 0; }
    if (t == 0) fl_cnt = 0;

    for (int g = 0; g < 4; ++g) {
        f32x4 acc[4][4];
#pragma unroll
        for (int mf = 0; mf < 4; ++mf)
#pragma unroll
            for (int nf = 0; nf < 4; ++nf) acc[mf][nf] = (f32x4){0.f, 0.f, 0.f, 0.f};
        float na[8] = {0.f,0.f,0.f,0.f,0.f,0.f,0.f,0.f};

        for (int kc = 0; kc < 8; ++kc) {
            __syncthreads();                   // previous compute done
            // ---- stage z tiles (bf16 planes, contiguous 16B per lane)
            {
                const int px = t >> 2, q = t & 3;
                const size_t src = (size_t)(n0 + px) * EDIM + kc * 32 + q * 8;
                *(uint4*)&zt[0][px][q << 3] = *(const uint4*)(zhi + src);
                *(uint4*)&zt[1][px][q << 3] = *(const uint4*)(zlo + src);
            }
            // ---- stage cb tile: f32 -> hi/lo, + norm partials
            {
                const int q = t & 7;           // 8 lanes per code row, 128B coalesced
#pragma unroll
                for (int i = 0; i < 8; ++i) {
                    const int cl = (i << 5) + (t >> 3);
                    const float4 v = *(const float4*)(cb + (size_t)((g << 8) + cl) * EDIM + kc * 32 + (q << 2));
                    na[i] = fmaf(v.x, v.x, fmaf(v.y, v.y, fmaf(v.z, v.z, fmaf(v.w, v.w, na[i]))));
                    const unsigned short h0 = f2bf(v.x), h1 = f2bf(v.y), h2 = f2bf(v.z), h3 = f2bf(v.w);
                    const unsigned short l0 = f2bf(v.x - bf2f(h0)), L1 = f2bf(v.y - bf2f(h1));
                    const unsigned short l2 = f2bf(v.z - bf2f(h2)), l3 = f2bf(v.w - bf2f(h3));
                    uint2 hw_, lw_;
                    hw_.x = (unsigned)h0 | ((unsigned)h1 << 16); hw_.y = (unsigned)h2 | ((unsigned)h3 << 16);
                    lw_.x = (unsigned)l0 | ((unsigned)L1 << 16); lw_.y = (unsigned)l2 | ((unsigned)l3 << 16);
                    *(uint2*)&cbt[0][cl][q << 2] = hw_;
                    *(uint2*)&cbt[1][cl][q << 2] = lw_;
                }
            }
            __syncthreads();
            // ---- compute: 16 ds_read_b128 + 48 MFMA
            s16x8 ah[4], bh[4], bl[4], al[4];
#pragma unroll
            for (int mf = 0; mf < 4; ++mf) ah[mf] = *(const s16x8*)&cbt[0][(w << 6) + (mf << 4) + l15][kq << 3];
#pragma unroll
            for (int nf = 0; nf < 4; ++nf) bh[nf] = *(const s16x8*)&zt[0][(nf << 4) + l15][kq << 3];
#pragma unroll
            for (int mf = 0; mf < 4; ++mf)
#pragma unroll
                for (int nf = 0; nf < 4; ++nf)
                    acc[mf][nf] = __builtin_amdgcn_mfma_f32_16x16x32_bf16(ah[mf], bh[nf], acc[mf][nf], 0, 0, 0);
#pragma unroll
            for (int nf = 0; nf < 4; ++nf) bl[nf] = *(const s16x8*)&zt[1][(nf << 4) + l15][kq << 3];
#pragma unroll
            for (int mf = 0; mf < 4; ++mf)
#pragma unroll
                for (int nf = 0; nf < 4; ++nf)
                    acc[mf][nf] = __builtin_amdgcn_mfma_f32_16x16x32_bf16(ah[mf], bl[nf], acc[mf][nf], 0, 0, 0);
#pragma unroll
            for (int mf = 0; mf < 4; ++mf) al[mf] = *(const s16x8*)&cbt[1][(w << 6) + (mf << 4) + l15][kq << 3];
#pragma unroll
            for (int mf = 0; mf < 4; ++mf)
#pragma unroll
                for (int nf = 0; nf < 4; ++nf)
                    acc[mf][nf] = __builtin_amdgcn_mfma_f32_16x16x32_bf16(al[mf], bh[nf], acc[mf][nf], 0, 0, 0);
        }
        // ---- finalize ||c||^2 for this group (8-lane shuffle reduce)
#pragma unroll
        for (int i = 0; i < 8; ++i) {
            float s = na[i];
            s += __shfl_xor(s, 1, 64);
            s += __shfl_xor(s, 2, 64);
            s += __shfl_xor(s, 4, 64);
            if ((t & 7) == 0) cn[(i << 5) + (t >> 3)] = s;
        }
        __syncthreads();
        // ---- top-2 update. D layout: col(px)=lane&15, row=(lane>>4)*4+r.
#pragma unroll
        for (int mf = 0; mf < 4; ++mf)
#pragma unroll
            for (int r = 0; r < 4; ++r) {
                const int local = (w << 6) + (mf << 4) + (kq << 2) + r;
                const float cnv = cn[local];
                const int code  = (g << 8) + local;     // ascending per lane
#pragma unroll
                for (int nf = 0; nf < 4; ++nf) {
                    const float d = fmaf(-2.f, acc[mf][nf][r], cnv);
                    if (d < b1[nf])      { b2[nf] = b1[nf]; i2[nf] = i1[nf]; b1[nf] = d; i1[nf] = code; }
                    else if (d < b2[nf]) { b2[nf] = d; i2[nf] = code; }
                }
            }
    }

    // ---- cross-lane merge (lanes p, p+16, p+32, p+48 share pixel col p)
#pragma unroll
    for (int nf = 0; nf < 4; ++nf) {
        float B1 = b1[nf], B2 = b2[nf]; int I1 = i1[nf], I2 = i2[nf];
#pragma unroll
        for (int m = 16; m <= 32; m <<= 1) {
            const float ob1 = __shfl_xor(B1, m, 64), ob2 = __shfl_xor(B2, m, 64);
            const int   oi1 = __shfl_xor(I1, m, 64), oi2 = __shfl_xor(I2, m, 64);
            if (ob1 < B1 || (ob1 == B1 && oi1 < I1)) {
                if (B1 < ob2 || (B1 == ob2 && I1 < oi2)) { B2 = B1; I2 = I1; }
                else                                      { B2 = ob2; I2 = oi2; }
                B1 = ob1; I1 = oi1;
            } else if (ob1 < B2 || (ob1 == B2 && oi1 < I2)) { B2 = ob1; I2 = oi1; }
        }
        if (lane < 16) {
            const int px = (nf << 4) + lane;
            rb1[w][px] = B1; rb2[w][px] = B2; ri1[w][px] = I1; ri2[w][px] = I2;
        }
    }
    __syncthreads();
    if (t < 64) {
        float B1 = rb1[0][t], B2 = rb2[0][t]; int I1 = ri1[0][t], I2 = ri2[0][t];
#pragma unroll
        for (int ww = 1; ww < 4; ++ww) {
            const float ob1 = rb1[ww][t], ob2 = rb2[ww][t];
            const int   oi1 = ri1[ww][t], oi2 = ri2[ww][t];
            if (ob1 < B1 || (ob1 == B1 && oi1 < I1)) {
                if (B1 < ob2 || (B1 == ob2 && I1 < oi2)) { B2 = B1; I2 = I1; }
                else                                      { B2 = ob2; I2 = oi2; }
                B1 = ob1; I1 = oi1;
            } else if (ob1 < B2 || (ob1 == B2 && oi1 < I2)) { B2 = ob1; I2 = oi1; }
        }
        if (B2 - B1 > THR) idx_out[n0 + t] = (float)I1;   // provably exact
        else {
            const int pos = atomicAdd(&fl_cnt, 1);
            fl_px[pos] = t; fl_i1[pos] = I1; fl_i2[pos] = I2;
        }
    }
    __syncthreads();
    // ---- exact fp32 fallback for near-tie pixels (expected ~0-1 per block)
    const int nfl = fl_cnt;
    for (int fi = 0; fi < nfl; ++fi) {
        const int px = fl_px[fi], ia = fl_i1[fi], ib = fl_i2[fi];
        const float zk = z[(size_t)bb * (EDIM * HWSZ) + t * HWSZ + hw0 + px];  // k = t
        const float da = zk - cb[(size_t)ia * EDIM + t];
        const float db = zk - cb[(size_t)ib * EDIM + t];
        float s1 = da * da, s2 = db * db;
#pragma unroll
        for (int m = 32; m; m >>= 1) { s1 += __shfl_xor(s1, m, 64); s2 += __shfl_xor(s2, m, 64); }
        if (lane == 0) { fred[0][w] = s1; fred[1][w] = s2; }
        __syncthreads();
        if (t == 0) {
            const float d1 = fred[0][0] + fred[0][1] + fred[0][2] + fred[0][3];
            const float d2 = fred[1][0] + fred[1][1] + fred[1][2] + fred[1][3];
            const int win = (d2 < d1 || (d2 == d1 && ib < ia)) ? ib : ia;
            idx_out[n0 + px] = (float)win;
        }
        __syncthreads();
    }
}

// ---------------------------------------------------------------------------
// Kernel 3: gather z_q = codebook[idx], transpose-store to (B,C,H,W), fused
// MSE loss: codebook_loss = (1 + BETA) * mean((z_q - z)^2), BETA = 0.25.
__global__ __launch_bounds__(256) void vq_gather(const float* __restrict__ z,
                                                 const float* __restrict__ cb,
                                                 const float* __restrict__ idxf,
                                                 float* __restrict__ out)
{
    __shared__ float lq[64][129];
    __shared__ int   sidx[64];

    const int t   = threadIdx.x;
    const int n0  = blockIdx.x << 6;
    const int bb  = n0 >> 10;
    const int hw0 = n0 & 1023;

    if (t < 64) sidx[t] = (int)idxf[n0 + t];

    const float* zb = z   + (size_t)bb * (EDIM * HWSZ) + hw0;
    float*       ob = out + (size_t)bb * (EDIM * HWSZ) + hw0;
    const int p  = t & 63;
    const int cq = t >> 6;
    float sum = 0.0f;

    for (int h = 0; h < 2; ++h) {
        __syncthreads();
#pragma unroll
        for (int i = 0; i < 8; ++i) {
            const int linear = (i << 8) + t;
            const int pr = linear >> 5;
            const int f4 = (linear & 31) << 2;
            const float4 v = *reinterpret_cast<const float4*>(
                cb + (size_t)sidx[pr] * EDIM + (h << 7) + f4);
            float* dst = &lq[pr][f4];
            dst[0] = v.x; dst[1] = v.y; dst[2] = v.z; dst[3] = v.w;
        }
        __syncthreads();
#pragma unroll 4
        for (int r = 0; r < 32; ++r) {
            const int c  = (r << 2) + cq;
            const int cf = (h << 7) + c;
            const float q  = lq[p][c];
            const float zv = zb[cf * HWSZ + p];
            ob[cf * HWSZ + p] = q;
            const float dd = q - zv;
            sum = fmaf(dd, dd, sum);
        }
    }

#pragma unroll
    for (int m = 32; m; m >>= 1) sum += __shfl_xor(sum, m, 64);
    if (p == 0) atomicAdd(out + LOSS_OFF, sum * (1.25f / 8388608.0f));
}

// ---------------------------------------------------------------------------
extern "C" void kernel_launch(void* const* d_in, const int* in_sizes, int n_in,
                              void* d_out, int out_size, void* d_ws, size_t ws_size,
                              hipStream_t stream)
{
    const float* z  = (const float*)d_in[0];
    const float* cb = (const float*)d_in[1];
    float* out = (float*)d_out;
    // bf16 hi/lo planes of z parked in the z_q region (exactly 32 MB; consumed
    // by vq_argmin, then overwritten by vq_gather).
    unsigned short* zhi = (unsigned short*)out;
    unsigned short* zlo = zhi + (size_t)NPIX * EDIM;

    vq_prep  <<<NPIX / 64, 256, 0, stream>>>(z, zhi, zlo, out + LOSS_OFF);
    vq_argmin<<<NPIX / 64, 256, 0, stream>>>(z, cb, zhi, zlo, out + IDX_OFF);
    vq_gather<<<NPIX / 64, 256, 0, stream>>>(z, cb, out + IDX_OFF, out);
}

// Round 6
// 198.198 us; speedup vs baseline: 3.3245x; 1.1337x over previous
//
#include <hip/hip_runtime.h>

// VQ-VAE vector quantization for z:(32,256,32,32) f32, codebook:(1024,256) f32.
// Outputs (flat f32 in d_out): z_q (B,C,H,W) [8388608] | loss [1] | indices as float [32768].
//
// Round 6: round-5 profile showed vq_argmin at 113us with MfmaUtil 18.7% /
// VALUBusy 49% / 4.19M LDS bank conflicts. Cause: every block re-converted the
// full 1 MB codebook f32->bf16 hi/lo (+norms) in the staging path (512x
// redundant), and the 64B-row LDS tiles gave 8-way conflicts on b128 frag reads.
// Changes:
//   - vq_cbsplit: one-time codebook hi/lo split, k-chunk-tiled [kc][code][32]
//     into d_ws (contiguous 16KB staging reads), + exact f32 norms.
//   - argmin LDS rows padded 32->40 ushorts (80B: 16B-aligned, 2-way-max reads);
//     staging uses 4-lanes-per-row mapping (near-uniform write banks).
//   - THR 0.02 -> 0.05 (larger provable-exactness margin; fallback is exact f32).
//   - ws_size guard: falls back to round-5 in-kernel-convert argmin if ws small.

#define EDIM   256
#define NCODE  1024
#define HWSZ   1024
#define NPIX   32768
#define LOSS_OFF 8388608
#define IDX_OFF  8388609
#define THR    0.05f
#define LROW   40      // padded LDS row stride in ushorts (80 B)

typedef __attribute__((ext_vector_type(8))) short s16x8;   // 8 bf16 = 4 VGPR (MFMA A/B frag)
typedef __attribute__((ext_vector_type(4))) float f32x4;   // MFMA C/D frag

__device__ inline unsigned short f2bf(float f) {           // RNE f32 -> bf16
    unsigned u = __float_as_uint(f);
    return (unsigned short)((u + 0x7FFFu + ((u >> 16) & 1u)) >> 16);
}
__device__ inline float bf2f(unsigned short h) { return __uint_as_float(((unsigned)h) << 16); }

// ---------------------------------------------------------------------------
// Kernel 0: one-time codebook split. hi_t/lo_t layout: [kc=k/32][code][k%32]
// so each (kc, 256-code group) staging read is 16 KB contiguous. Also exact
// f32 norms. 128 blocks x 256 thr; block handles 8 codes; thread: 8 k-elems.
__global__ __launch_bounds__(256) void vq_cbsplit(const float* __restrict__ cb,
                                                  unsigned short* __restrict__ hi_t,
                                                  unsigned short* __restrict__ lo_t,
                                                  float* __restrict__ cnorm)
{
    const int t    = threadIdx.x;
    const int code = (blockIdx.x << 3) + (t >> 5);
    const int kg   = t & 31;                  // k = kg*8 .. kg*8+7
    const float4 v0 = *(const float4*)(cb + (size_t)code * EDIM + (kg << 3));
    const float4 v1 = *(const float4*)(cb + (size_t)code * EDIM + (kg << 3) + 4);

    float s = v0.x*v0.x + v0.y*v0.y + v0.z*v0.z + v0.w*v0.w
            + v1.x*v1.x + v1.y*v1.y + v1.z*v1.z + v1.w*v1.w;
    s += __shfl_xor(s, 1, 64);  s += __shfl_xor(s, 2, 64);
    s += __shfl_xor(s, 4, 64);  s += __shfl_xor(s, 8, 64);
    s += __shfl_xor(s, 16, 64);                 // sum over the code's 32 lanes
    if (kg == 0) cnorm[code] = s;

    const float f[8] = {v0.x, v0.y, v0.z, v0.w, v1.x, v1.y, v1.z, v1.w};
    unsigned short h[8], l[8];
#pragma unroll
    for (int j = 0; j < 8; ++j) { h[j] = f2bf(f[j]); l[j] = f2bf(f[j] - bf2f(h[j])); }
    uint4 H, L;
    H.x = (unsigned)h[0] | ((unsigned)h[1] << 16);  H.y = (unsigned)h[2] | ((unsigned)h[3] << 16);
    H.z = (unsigned)h[4] | ((unsigned)h[5] << 16);  H.w = (unsigned)h[6] | ((unsigned)h[7] << 16);
    L.x = (unsigned)l[0] | ((unsigned)l[1] << 16);  L.y = (unsigned)l[2] | ((unsigned)l[3] << 16);
    L.z = (unsigned)l[4] | ((unsigned)l[5] << 16);  L.w = (unsigned)l[6] | ((unsigned)l[7] << 16);
    const size_t off = ((size_t)(kg >> 2) * NCODE + code) * 32 + ((kg & 3) << 3);
    *(uint4*)(hi_t + off) = H;
    *(uint4*)(lo_t + off) = L;
}

// ---------------------------------------------------------------------------
// Kernel 1: transpose z (B,C,HW) f32 -> pixel-major bf16 planes zhi[n][k],
// zlo[n][k] (n = b*1024+hw, k = channel). Also zeroes the loss slot.
__global__ __launch_bounds__(256) void vq_prep(const float* __restrict__ z,
                                               unsigned short* __restrict__ zhi,
                                               unsigned short* __restrict__ zlo,
                                               float* __restrict__ loss_slot)
{
    __shared__ unsigned lzp[64][68];          // packed hi|lo<<16, 64 px x 64 k slab

    const int t  = threadIdx.x;
    const int n0 = blockIdx.x << 6;           // 512 blocks x 64 px
    const int bb = n0 >> 10, hw0 = n0 & 1023;
    if (blockIdx.x == 0 && t == 0) *loss_slot = 0.0f;
    const float* zb = z + (size_t)bb * (EDIM * HWSZ) + hw0;

    for (int pk = 0; pk < 4; ++pk) {          // 4 k-slabs of 64
#pragma unroll
        for (int i = 0; i < 4; ++i) {         // 64k x 64px = 1024 float4
            const int linear = (i << 8) + t;
            const int kk  = linear >> 4;
            const int px4 = (linear & 15) << 2;
            const float4 v = *reinterpret_cast<const float4*>(zb + (pk * 64 + kk) * HWSZ + px4);
            const float vv[4] = {v.x, v.y, v.z, v.w};
#pragma unroll
            for (int j = 0; j < 4; ++j) {
                const unsigned short h = f2bf(vv[j]);
                const unsigned short l = f2bf(vv[j] - bf2f(h));
                lzp[px4 + j][kk] = (unsigned)h | ((unsigned)l << 16);
            }
        }
        __syncthreads();
        {
            const int px = t >> 2, kq = (t & 3) << 4;     // 16 k per thread
            const uint4 q0 = *(const uint4*)&lzp[px][kq];
            const uint4 q1 = *(const uint4*)&lzp[px][kq + 4];
            const uint4 q2 = *(const uint4*)&lzp[px][kq + 8];
            const uint4 q3 = *(const uint4*)&lzp[px][kq + 12];
            #define PH(a,b) (((a) & 0xffffu) | ((b) << 16))
            #define PL(a,b) (((a) >> 16) | ((b) & 0xffff0000u))
            const uint4 hA = {PH(q0.x,q0.y), PH(q0.z,q0.w), PH(q1.x,q1.y), PH(q1.z,q1.w)};
            const uint4 hB = {PH(q2.x,q2.y), PH(q2.z,q2.w), PH(q3.x,q3.y), PH(q3.z,q3.w)};
            const uint4 lA = {PL(q0.x,q0.y), PL(q0.z,q0.w), PL(q1.x,q1.y), PL(q1.z,q1.w)};
            const uint4 lB = {PL(q2.x,q2.y), PL(q2.z,q2.w), PL(q3.x,q3.y), PL(q3.z,q3.w)};
            #undef PH
            #undef PL
            const size_t off = (size_t)(n0 + px) * EDIM + pk * 64 + kq;
            *(uint4*)(zhi + off)     = hA;  *(uint4*)(zhi + off + 8) = hB;
            *(uint4*)(zlo + off)     = lA;  *(uint4*)(zlo + off + 8) = lB;
        }
        __syncthreads();
    }
}

// ---------------------------------------------------------------------------
// Kernel 2 (fast path): MFMA distance GEMM + exact argmin, pre-split codebook.
// Block: 256 thr (4 waves) x 64 pixels x all 1024 codes (4 groups of 256).
__global__ __launch_bounds__(256, 2) void vq_argmin_pre(
    const float* __restrict__ z, const float* __restrict__ cb,
    const unsigned short* __restrict__ zhi, const unsigned short* __restrict__ zlo,
    const unsigned short* __restrict__ hi_t, const unsigned short* __restrict__ lo_t,
    const float* __restrict__ cnorm, float* __restrict__ idx_out)
{
    __shared__ unsigned short cbt[2][256][LROW]; // [hi/lo][code][k] 40 KiB
    __shared__ unsigned short zt [2][64][LROW];  // [hi/lo][px][k]   10 KiB
    __shared__ float cn[NCODE];                  // 4 KiB
    __shared__ float rb1[4][64], rb2[4][64];
    __shared__ int   ri1[4][64], ri2[4][64];
    __shared__ int   fl_cnt, fl_px[64], fl_i1[64], fl_i2[64];
    __shared__ float fred[2][4];

    const int t    = threadIdx.x;
    const int lane = t & 63;
    const int w    = t >> 6;
    const int n0   = blockIdx.x << 6;          // 512 blocks
    const int bb   = n0 >> 10, hw0 = n0 & 1023;
    const int l15  = lane & 15, kq = lane >> 4;
    const int row4 = t >> 2, slot = t & 3;     // staging: 4 lanes per row

#pragma unroll
    for (int i = 0; i < 4; ++i) cn[(i << 8) + t] = cnorm[(i << 8) + t];
    if (t == 0) fl_cnt = 0;

    float b1[4], b2[4]; int i1[4], i2[4];
#pragma unroll
    for (int nf = 0; nf < 4; ++nf) { b1[nf] = 3.402823e38f; b2[nf] = 3.402823e38f; i1[nf] = 0; i2[nf] = 0; }

    for (int g = 0; g < 4; ++g) {
        f32x4 acc[4][4];
#pragma unroll
        for (int mf = 0; mf < 4; ++mf)
#pragma unroll
            for (int nf = 0; nf < 4; ++nf) acc[mf][nf] = (f32x4){0.f, 0.f, 0.f, 0.f};

        for (int kc = 0; kc < 8; ++kc) {
            __syncthreads();                   // previous compute done
            // ---- stage cb tile: contiguous 16KB/plane, coalesced uint4 loads
            {
                const size_t tbase = ((size_t)kc * NCODE + (g << 8)) * 32;
#pragma unroll
                for (int ps = 0; ps < 4; ++ps) {
                    const int row = (ps << 6) + row4;
                    const size_t goff = tbase + ((size_t)row << 5) + (slot << 3);
                    *(uint4*)&cbt[0][row][slot << 3] = *(const uint4*)(hi_t + goff);
                    *(uint4*)&cbt[1][row][slot << 3] = *(const uint4*)(lo_t + goff);
                }
            }
            // ---- stage z tile (pixel-major bf16 planes)
            {
                const size_t src = (size_t)(n0 + row4) * EDIM + kc * 32 + (slot << 3);
                *(uint4*)&zt[0][row4][slot << 3] = *(const uint4*)(zhi + src);
                *(uint4*)&zt[1][row4][slot << 3] = *(const uint4*)(zlo + src);
            }
            __syncthreads();
            // ---- compute: 16 ds_read_b128 + 48 MFMA
            s16x8 ah[4], bh[4], bl[4], al[4];
#pragma unroll
            for (int mf = 0; mf < 4; ++mf) ah[mf] = *(const s16x8*)&cbt[0][(w << 6) + (mf << 4) + l15][kq << 3];
#pragma unroll
            for (int nf = 0; nf < 4; ++nf) bh[nf] = *(const s16x8*)&zt[0][(nf << 4) + l15][kq << 3];
#pragma unroll
            for (int mf = 0; mf < 4; ++mf)
#pragma unroll
                for (int nf = 0; nf < 4; ++nf)
                    acc[mf][nf] = __builtin_amdgcn_mfma_f32_16x16x32_bf16(ah[mf], bh[nf], acc[mf][nf], 0, 0, 0);
#pragma unroll
            for (int nf = 0; nf < 4; ++nf) bl[nf] = *(const s16x8*)&zt[1][(nf << 4) + l15][kq << 3];
#pragma unroll
            for (int mf = 0; mf < 4; ++mf)
#pragma unroll
                for (int nf = 0; nf < 4; ++nf)
                    acc[mf][nf] = __builtin_amdgcn_mfma_f32_16x16x32_bf16(ah[mf], bl[nf], acc[mf][nf], 0, 0, 0);
#pragma unroll
            for (int mf = 0; mf < 4; ++mf) al[mf] = *(const s16x8*)&cbt[1][(w << 6) + (mf << 4) + l15][kq << 3];
#pragma unroll
            for (int mf = 0; mf < 4; ++mf)
#pragma unroll
                for (int nf = 0; nf < 4; ++nf)
                    acc[mf][nf] = __builtin_amdgcn_mfma_f32_16x16x32_bf16(al[mf], bh[nf], acc[mf][nf], 0, 0, 0);
        }
        // ---- top-2 update. D layout: col(px)=lane&15, row=(lane>>4)*4+r.
#pragma unroll
        for (int mf = 0; mf < 4; ++mf)
#pragma unroll
            for (int r = 0; r < 4; ++r) {
                const int local = (w << 6) + (mf << 4) + (kq << 2) + r;
                const float cnv = cn[(g << 8) + local];
                const int code  = (g << 8) + local;     // ascending per lane
#pragma unroll
                for (int nf = 0; nf < 4; ++nf) {
                    const float d = fmaf(-2.f, acc[mf][nf][r], cnv);
                    if (d < b1[nf])      { b2[nf] = b1[nf]; i2[nf] = i1[nf]; b1[nf] = d; i1[nf] = code; }
                    else if (d < b2[nf]) { b2[nf] = d; i2[nf] = code; }
                }
            }
    }

    // ---- cross-lane merge (lanes p, p+16, p+32, p+48 share pixel col p)
#pragma unroll
    for (int nf = 0; nf < 4; ++nf) {
        float B1 = b1[nf], B2 = b2[nf]; int I1 = i1[nf], I2 = i2[nf];
#pragma unroll
        for (int m = 16; m <= 32; m <<= 1) {
            const float ob1 = __shfl_xor(B1, m, 64), ob2 = __shfl_xor(B2, m, 64);
            const int   oi1 = __shfl_xor(I1, m, 64), oi2 = __shfl_xor(I2, m, 64);
            if (ob1 < B1 || (ob1 == B1 && oi1 < I1)) {
                if (B1 < ob2 || (B1 == ob2 && I1 < oi2)) { B2 = B1; I2 = I1; }
                else                                      { B2 = ob2; I2 = oi2; }
                B1 = ob1; I1 = oi1;
            } else if (ob1 < B2 || (ob1 == B2 && oi1 < I2)) { B2 = ob1; I2 = oi1; }
        }
        if (lane < 16) {
            const int px = (nf << 4) + lane;
            rb1[w][px] = B1; rb2[w][px] = B2; ri1[w][px] = I1; ri2[w][px] = I2;
        }
    }
    __syncthreads();
    if (t < 64) {
        float B1 = rb1[0][t], B2 = rb2[0][t]; int I1 = ri1[0][t], I2 = ri2[0][t];
#pragma unroll
        for (int ww = 1; ww < 4; ++ww) {
            const float ob1 = rb1[ww][t], ob2 = rb2[ww][t];
            const int   oi1 = ri1[ww][t], oi2 = ri2[ww][t];
            if (ob1 < B1 || (ob1 == B1 && oi1 < I1)) {
                if (B1 < ob2 || (B1 == ob2 && I1 < oi2)) { B2 = B1; I2 = I1; }
                else                                      { B2 = ob2; I2 = oi2; }
                B1 = ob1; I1 = oi1;
            } else if (ob1 < B2 || (ob1 == B2 && oi1 < I2)) { B2 = ob1; I2 = oi1; }
        }
        if (B2 - B1 > THR) idx_out[n0 + t] = (float)I1;   // provably exact
        else {
            const int pos = atomicAdd(&fl_cnt, 1);
            fl_px[pos] = t; fl_i1[pos] = I1; fl_i2[pos] = I2;
        }
    }
    __syncthreads();
    // ---- exact fp32 fallback for near-tie pixels (expected ~1-2 per block)
    const int nfl = fl_cnt;
    for (int fi = 0; fi < nfl; ++fi) {
        const int px = fl_px[fi], ia = fl_i1[fi], ib = fl_i2[fi];
        const float zk = z[(size_t)bb * (EDIM * HWSZ) + t * HWSZ + hw0 + px];  // k = t
        const float da = zk - cb[(size_t)ia * EDIM + t];
        const float db = zk - cb[(size_t)ib * EDIM + t];
        float s1 = da * da, s2 = db * db;
#pragma unroll
        for (int m = 32; m; m >>= 1) { s1 += __shfl_xor(s1, m, 64); s2 += __shfl_xor(s2, m, 64); }
        if (lane == 0) { fred[0][w] = s1; fred[1][w] = s2; }
        __syncthreads();
        if (t == 0) {
            const float d1 = fred[0][0] + fred[0][1] + fred[0][2] + fred[0][3];
            const float d2 = fred[1][0] + fred[1][1] + fred[1][2] + fred[1][3];
            const int win = (d2 < d1 || (d2 == d1 && ib < ia)) ? ib : ia;
            idx_out[n0 + px] = (float)win;
        }
        __syncthreads();
    }
}

// ---------------------------------------------------------------------------
// Kernel 2 (fallback, ws too small): round-5 in-kernel-convert variant.
__global__ __launch_bounds__(256, 2) void vq_argmin_cv(const float* __restrict__ z,
                                                       const float* __restrict__ cb,
                                                       const unsigned short* __restrict__ zhi,
                                                       const unsigned short* __restrict__ zlo,
                                                       float* __restrict__ idx_out)
{
    __shared__ unsigned short cbt[2][256][32];
    __shared__ unsigned short zt [2][64][32];
    __shared__ float cn[256];
    __shared__ float rb1[4][64], rb2[4][64];
    __shared__ int   ri1[4][64], ri2[4][64];
    __shared__ int   fl_cnt, fl_px[64], fl_i1[64], fl_i2[64];
    __shared__ float fred[2][4];

    const int t    = threadIdx.x;
    const int lane = t & 63;
    const int w    = t >> 6;
    const int n0   = blockIdx.x << 6;
    const int bb   = n0 >> 10, hw0 = n0 & 1023;
    const int l15  = lane & 15, kq = lane >> 4;

    float b1[4], b2[4]; int i1[4], i2[4];
#pragma unroll
    for (int nf = 0; nf < 4; ++nf) { b1[nf] = 3.402823e38f; b2[nf] = 3.402823e38f; i1[nf] = 0; i2[nf] = 0; }
    if (t == 0) fl_cnt = 0;

    for (int g = 0; g < 4; ++g) {
        f32x4 acc[4][4];
#pragma unroll
        for (int mf = 0; mf < 4; ++mf)
#pragma unroll
            for (int nf = 0; nf < 4; ++nf) acc[mf][nf] = (f32x4){0.f, 0.f, 0.f, 0.f};
        float na[8] = {0.f,0.f,0.f,0.f,0.f,0.f,0.f,0.f};

        for (int kc = 0; kc < 8; ++kc) {
            __syncthreads();
            {
                const int px = t >> 2, q = t & 3;
                const size_t src = (size_t)(n0 + px) * EDIM + kc * 32 + q * 8;
                *(uint4*)&zt[0][px][q << 3] = *(const uint4*)(zhi + src);
                *(uint4*)&zt[1][px][q << 3] = *(const uint4*)(zlo + src);
            }
            {
                const int q = t & 7;
#pragma unroll
                for (int i = 0; i < 8; ++i) {
                    const int cl = (i << 5) + (t >> 3);
                    const float4 v = *(const float4*)(cb + (size_t)((g << 8) + cl) * EDIM + kc * 32 + (q << 2));
                    na[i] = fmaf(v.x, v.x, fmaf(v.y, v.y, fmaf(v.z, v.z, fmaf(v.w, v.w, na[i]))));
                    const unsigned short h0 = f2bf(v.x), h1 = f2bf(v.y), h2 = f2bf(v.z), h3 = f2bf(v.w);
                    const unsigned short l0 = f2bf(v.x - bf2f(h0)), L1 = f2bf(v.y - bf2f(h1));
                    const unsigned short l2 = f2bf(v.z - bf2f(h2)), l3 = f2bf(v.w - bf2f(h3));
                    uint2 hw_, lw_;
                    hw_.x = (unsigned)h0 | ((unsigned)h1 << 16); hw_.y = (unsigned)h2 | ((unsigned)h3 << 16);
                    lw_.x = (unsigned)l0 | ((unsigned)L1 << 16); lw_.y = (unsigned)l2 | ((unsigned)l3 << 16);
                    *(uint2*)&cbt[0][cl][q << 2] = hw_;
                    *(uint2*)&cbt[1][cl][q << 2] = lw_;
                }
            }
            __syncthreads();
            s16x8 ah[4], bh[4], bl[4], al[4];
#pragma unroll
            for (int mf = 0; mf < 4; ++mf) ah[mf] = *(const s16x8*)&cbt[0][(w << 6) + (mf << 4) + l15][kq << 3];
#pragma unroll
            for (int nf = 0; nf < 4; ++nf) bh[nf] = *(const s16x8*)&zt[0][(nf << 4) + l15][kq << 3];
#pragma unroll
            for (int mf = 0; mf < 4; ++mf)
#pragma unroll
                for (int nf = 0; nf < 4; ++nf)
                    acc[mf][nf] = __builtin_amdgcn_mfma_f32_16x16x32_bf16(ah[mf], bh[nf], acc[mf][nf], 0, 0, 0);
#pragma unroll
            for (int nf = 0; nf < 4; ++nf) bl[nf] = *(const s16x8*)&zt[1][(nf << 4) + l15][kq << 3];
#pragma unroll
            for (int mf = 0; mf < 4; ++mf)
#pragma unroll
                for (int nf = 0; nf < 4; ++nf)
                    acc[mf][nf] = __builtin_amdgcn_mfma_f32_16x16x32_bf16(ah[mf], bl[nf], acc[mf][nf], 0, 0, 0);
#pragma unroll
            for (int mf = 0; mf < 4; ++mf) al[mf] = *(const s16x8*)&cbt[1][(w << 6) + (mf << 4) + l15][kq << 3];
#pragma unroll
            for (int mf = 0; mf < 4; ++mf)
#pragma unroll
                for (int nf = 0; nf < 4; ++nf)
                    acc[mf][nf] = __builtin_amdgcn_mfma_f32_16x16x32_bf16(al[mf], bh[nf], acc[mf][nf], 0, 0, 0);
        }
#pragma unroll
        for (int i = 0; i < 8; ++i) {
            float s = na[i];
            s += __shfl_xor(s, 1, 64);
            s += __shfl_xor(s, 2, 64);
            s += __shfl_xor(s, 4, 64);
            if ((t & 7) == 0) cn[(i << 5) + (t >> 3)] = s;
        }
        __syncthreads();
#pragma unroll
        for (int mf = 0; mf < 4; ++mf)
#pragma unroll
            for (int r = 0; r < 4; ++r) {
                const int local = (w << 6) + (mf << 4) + (kq << 2) + r;
                const float cnv = cn[local];
                const int code  = (g << 8) + local;
#pragma unroll
                for (int nf = 0; nf < 4; ++nf) {
                    const float d = fmaf(-2.f, acc[mf][nf][r], cnv);
                    if (d < b1[nf])      { b2[nf] = b1[nf]; i2[nf] = i1[nf]; b1[nf] = d; i1[nf] = code; }
                    else if (d < b2[nf]) { b2[nf] = d; i2[nf] = code; }
                }
            }
    }

#pragma unroll
    for (int nf = 0; nf < 4; ++nf) {
        float B1 = b1[nf], B2 = b2[nf]; int I1 = i1[nf], I2 = i2[nf];
#pragma unroll
        for (int m = 16; m <= 32; m <<= 1) {
            const float ob1 = __shfl_xor(B1, m, 64), ob2 = __shfl_xor(B2, m, 64);
            const int   oi1 = __shfl_xor(I1, m, 64), oi2 = __shfl_xor(I2, m, 64);
            if (ob1 < B1 || (ob1 == B1 && oi1 < I1)) {
                if (B1 < ob2 || (B1 == ob2 && I1 < oi2)) { B2 = B1; I2 = I1; }
                else                                      { B2 = ob2; I2 = oi2; }
                B1 = ob1; I1 = oi1;
            } else if (ob1 < B2 || (ob1 == B2 && oi1 < I2)) { B2 = ob1; I2 = oi1; }
        }
        if (lane < 16) {
            const int px = (nf << 4) + lane;
            rb1[w][px] = B1; rb2[w][px] = B2; ri1[w][px] = I1; ri2[w][px] = I2;
        }
    }
    __syncthreads();
    if (t < 64) {
        float B1 = rb1[0][t], B2 = rb2[0][t]; int I1 = ri1[0][t], I2 = ri2[0][t];
#pragma unroll
        for (int ww = 1; ww < 4; ++ww) {
            const float ob1 = rb1[ww][t], ob2 = rb2[ww][t];
            const int   oi1 = ri1[ww][t], oi2 = ri2[ww][t];
            if (ob1 < B1 || (ob1 == B1 && oi1 < I1)) {
                if (B1 < ob2 || (B1 == ob2 && I1 < oi2)) { B2 = B1; I2 = I1; }
                else                                      { B2 = ob2; I2 = oi2; }
                B1 = ob1; I1 = oi1;
            } else if (ob1 < B2 || (ob1 == B2 && oi1 < I2)) { B2 = ob1; I2 = oi1; }
        }
        if (B2 - B1 > THR) idx_out[n0 + t] = (float)I1;
        else {
            const int pos = atomicAdd(&fl_cnt, 1);
            fl_px[pos] = t; fl_i1[pos] = I1; fl_i2[pos] = I2;
        }
    }
    __syncthreads();
    const int nfl = fl_cnt;
    for (int fi = 0; fi < nfl; ++fi) {
        const int px = fl_px[fi], ia = fl_i1[fi], ib = fl_i2[fi];
        const float zk = z[(size_t)bb * (EDIM * HWSZ) + t * HWSZ + hw0 + px];
        const float da = zk - cb[(size_t)ia * EDIM + t];
        const float db = zk - cb[(size_t)ib * EDIM + t];
        float s1 = da * da, s2 = db * db;
#pragma unroll
        for (int m = 32; m; m >>= 1) { s1 += __shfl_xor(s1, m, 64); s2 += __shfl_xor(s2, m, 64); }
        if (lane == 0) { fred[0][w] = s1; fred[1][w] = s2; }
        __syncthreads();
        if (t == 0) {
            const float d1 = fred[0][0] + fred[0][1] + fred[0][2] + fred[0][3];
            const float d2 = fred[1][0] + fred[1][1] + fred[1][2] + fred[1][3];
            const int win = (d2 < d1 || (d2 == d1 && ib < ia)) ? ib : ia;
            idx_out[n0 + px] = (float)win;
        }
        __syncthreads();
    }
}

// ---------------------------------------------------------------------------
// Kernel 3: gather z_q = codebook[idx], transpose-store to (B,C,H,W), fused
// MSE loss: codebook_loss = (1 + BETA) * mean((z_q - z)^2), BETA = 0.25.
__global__ __launch_bounds__(256) void vq_gather(const float* __restrict__ z,
                                                 const float* __restrict__ cb,
                                                 const float* __restrict__ idxf,
                                                 float* __restrict__ out)
{
    __shared__ float lq[64][129];
    __shared__ int   sidx[64];

    const int t   = threadIdx.x;
    const int n0  = blockIdx.x << 6;
    const int bb  = n0 >> 10;
    const int hw0 = n0 & 1023;

    if (t < 64) sidx[t] = (int)idxf[n0 + t];

    const float* zb = z   + (size_t)bb * (EDIM * HWSZ) + hw0;
    float*       ob = out + (size_t)bb * (EDIM * HWSZ) + hw0;
    const int p  = t & 63;
    const int cq = t >> 6;
    float sum = 0.0f;

    for (int h = 0; h < 2; ++h) {
        __syncthreads();
#pragma unroll
        for (int i = 0; i < 8; ++i) {
            const int linear = (i << 8) + t;
            const int pr = linear >> 5;
            const int f4 = (linear & 31) << 2;
            const float4 v = *reinterpret_cast<const float4*>(
                cb + (size_t)sidx[pr] * EDIM + (h << 7) + f4);
            float* dst = &lq[pr][f4];
            dst[0] = v.x; dst[1] = v.y; dst[2] = v.z; dst[3] = v.w;
        }
        __syncthreads();
#pragma unroll 4
        for (int r = 0; r < 32; ++r) {
            const int c  = (r << 2) + cq;
            const int cf = (h << 7) + c;
            const float q  = lq[p][c];
            const float zv = zb[cf * HWSZ + p];
            ob[cf * HWSZ + p] = q;
            const float dd = q - zv;
            sum = fmaf(dd, dd, sum);
        }
    }

#pragma unroll
    for (int m = 32; m; m >>= 1) sum += __shfl_xor(sum, m, 64);
    if (p == 0) atomicAdd(out + LOSS_OFF, sum * (1.25f / 8388608.0f));
}

// ---------------------------------------------------------------------------
extern "C" void kernel_launch(void* const* d_in, const int* in_sizes, int n_in,
                              void* d_out, int out_size, void* d_ws, size_t ws_size,
                              hipStream_t stream)
{
    const float* z  = (const float*)d_in[0];
    const float* cb = (const float*)d_in[1];
    float* out = (float*)d_out;
    // bf16 hi/lo planes of z parked in the z_q region (exactly 32 MB; consumed
    // by vq_argmin, then overwritten by vq_gather).
    unsigned short* zhi = (unsigned short*)out;
    unsigned short* zlo = zhi + (size_t)NPIX * EDIM;

    // Pre-split codebook in d_ws: hi_t (512 KB) | lo_t (512 KB) | cnorm (4 KB).
    const size_t plane = (size_t)8 * NCODE * 32;                // ushorts per plane
    const size_t need  = plane * 2 * sizeof(unsigned short) + NCODE * sizeof(float);

    if (ws_size >= need) {
        unsigned short* hi_t = (unsigned short*)d_ws;
        unsigned short* lo_t = hi_t + plane;
        float*          cnp  = (float*)(lo_t + plane);
        vq_cbsplit   <<<NCODE / 8, 256, 0, stream>>>(cb, hi_t, lo_t, cnp);
        vq_prep      <<<NPIX / 64, 256, 0, stream>>>(z, zhi, zlo, out + LOSS_OFF);
        vq_argmin_pre<<<NPIX / 64, 256, 0, stream>>>(z, cb, zhi, zlo, hi_t, lo_t, cnp, out + IDX_OFF);
    } else {
        vq_prep      <<<NPIX / 64, 256, 0, stream>>>(z, zhi, zlo, out + LOSS_OFF);
        vq_argmin_cv <<<NPIX / 64, 256, 0, stream>>>(z, cb, zhi, zlo, out + IDX_OFF);
    }
    vq_gather<<<NPIX / 64, 256, 0, stream>>>(z, cb, out + IDX_OFF, out);
}